// Round 8
// baseline (1152.113 us; speedup 1.0000x reference)
//
#include <hip/hip_runtime.h>
#include <stdint.h>

// Problem constants
#define T_TOKENS 16384
#define H_DIM 1024
#define E_NUM 8
#define DFF_DIM 4096

// GEMM tiling
#define BMT 128
#define BNT 128
#define BKT 64
#define MT_CAP 264                       // max padded m-tiles: ceil((32768+8*127)/128)
#define PAD_ROWS (MT_CAP * BMT)          // 33792
#define NCHUNK 8
#define MT_PER_CHUNK (MT_CAP / NCHUNK)   // 33
#define CHUNK_ROWS (MT_PER_CHUNK * BMT)  // 4224
#define CHUNK_ELEMS ((size_t)CHUNK_ROWS * DFF_DIM)  // 17,301,504 bf16

// Workspace layout (bytes) — identical to round 7 (hdn now = 2 x 34.6MB dbuf)
#define WS_COUNTS     0
#define WS_CURSOR     32
#define WS_OFFS       64
#define WS_SLOT_TOK   256
#define WS_SLOT_W     135424
#define WS_EIDX       270592
#define WS_EW         401664
#define WS_WC1        532736
#define WS_WC2        67641600
#define WS_XB         134750464
#define WS_HDN        168304896          // 2 x CHUNK_ROWS x DFF bf16 = 69,206,016
#define WS_OUTK1      237510912          // T x H bf16 = 33,554,432
#define WS_REQUIRED   271065344UL        // <= 273,162,496 proven available
#define WS_SMALL_ZERO 270592

typedef __attribute__((ext_vector_type(8))) short short8;
typedef __attribute__((ext_vector_type(4))) float f32x4;

__device__ __forceinline__ unsigned short f2bf(float f) {
  union { float f; unsigned int u; } v; v.f = f;
  unsigned int r = v.u + 0x7FFFu + ((v.u >> 16) & 1u);  // round-nearest-even
  return (unsigned short)(r >> 16);
}

__device__ __forceinline__ float bf2f(unsigned short b) {
  union { unsigned int u; float f; } v; v.u = ((unsigned int)b) << 16;
  return v.f;
}

__device__ __forceinline__ void load_lds16(const void* g, void* l) {
  __builtin_amdgcn_global_load_lds(
      (const __attribute__((address_space(1))) void*)g,
      (__attribute__((address_space(3))) void*)l, 16, 0, 0);
}

// ---------------------------------------------------------------------------
// Weight fp32 -> bf16 conversion
// ---------------------------------------------------------------------------
__global__ void convert_weights(const float* __restrict__ w1,
                                const float* __restrict__ w2,
                                unsigned short* __restrict__ wc1,
                                unsigned short* __restrict__ wc2) {
  int i = blockIdx.x * blockDim.x + threadIdx.x;
  const float4* s1 = (const float4*)w1;
  const float4* s2 = (const float4*)w2;
  float4 a = s1[i];
  float4 b = s2[i];
  ushort4 ua, ub;
  ua.x = f2bf(a.x); ua.y = f2bf(a.y); ua.z = f2bf(a.z); ua.w = f2bf(a.w);
  ub.x = f2bf(b.x); ub.y = f2bf(b.y); ub.z = f2bf(b.z); ub.w = f2bf(b.w);
  ((ushort4*)wc1)[i] = ua;
  ((ushort4*)wc2)[i] = ub;
}

// ---------------------------------------------------------------------------
// Router: no global atomics (round-2 lesson). Emits x as bf16 (xb).
// ---------------------------------------------------------------------------
__global__ __launch_bounds__(256) void router_kernel(
    const float* __restrict__ x, const float* __restrict__ rw,
    const float* __restrict__ rb, unsigned short* __restrict__ xb,
    int* __restrict__ eidx, float* __restrict__ ew) {
  __shared__ float4 rws[E_NUM * 256];
  const int tid = threadIdx.x;
#pragma unroll
  for (int k = 0; k < 8; ++k) rws[k * 256 + tid] = ((const float4*)rw)[k * 256 + tid];
  __syncthreads();

  const int wave = tid >> 6;
  const int lane = tid & 63;
#pragma unroll
  for (int i = 0; i < 4; ++i) {
    const int t = blockIdx.x * 16 + wave * 4 + i;
    const float4* xrow = (const float4*)(x + (size_t)t * H_DIM);
    float4 xv[4];
#pragma unroll
    for (int j = 0; j < 4; ++j) xv[j] = xrow[j * 64 + lane];

    ushort4* xbrow = (ushort4*)(xb + (size_t)t * H_DIM);
#pragma unroll
    for (int j = 0; j < 4; ++j) {
      ushort4 o;
      o.x = f2bf(xv[j].x); o.y = f2bf(xv[j].y);
      o.z = f2bf(xv[j].z); o.w = f2bf(xv[j].w);
      xbrow[j * 64 + lane] = o;
    }

    float s[E_NUM];
#pragma unroll
    for (int e = 0; e < E_NUM; ++e) {
      float a = 0.f;
#pragma unroll
      for (int j = 0; j < 4; ++j) {
        float4 wv = rws[e * 256 + j * 64 + lane];
        a += xv[j].x * wv.x + xv[j].y * wv.y + xv[j].z * wv.z + xv[j].w * wv.w;
      }
      s[e] = a;
    }
#pragma unroll
    for (int off = 32; off; off >>= 1) {
#pragma unroll
      for (int e = 0; e < E_NUM; ++e) s[e] += __shfl_xor(s[e], off);
    }
    if (lane == 0) {
      float lg[E_NUM];
#pragma unroll
      for (int e = 0; e < E_NUM; ++e) lg[e] = s[e] + rb[e];
      int i0 = 0; float m0 = lg[0];
#pragma unroll
      for (int e = 1; e < E_NUM; ++e)
        if (lg[e] > m0) { m0 = lg[e]; i0 = e; }
      int i1 = -1; float m1 = -3.4e38f;
#pragma unroll
      for (int e = 0; e < E_NUM; ++e)
        if (e != i0 && lg[e] > m1) { m1 = lg[e]; i1 = e; }
      float e1 = expf(m1 - m0);
      float denom = 1.f + e1;
      ((int2*)eidx)[t] = make_int2(i0, i1);
      ((float2*)ew)[t] = make_float2(1.f / denom, e1 / denom);
    }
  }
}

// ---------------------------------------------------------------------------
// count_kernel: single block, register histogram, LDS atomics only.
// ---------------------------------------------------------------------------
__global__ __launch_bounds__(1024) void count_kernel(const int* __restrict__ eidx,
                                                     int* __restrict__ counts,
                                                     int* __restrict__ offs,
                                                     int* __restrict__ cursor) {
  __shared__ int hist[E_NUM];
  const int tid = threadIdx.x;
  const int lane = tid & 63;
  if (tid < E_NUM) hist[tid] = 0;
  __syncthreads();
  int c[E_NUM];
#pragma unroll
  for (int e = 0; e < E_NUM; ++e) c[e] = 0;
  const int4* p = (const int4*)eidx;
#pragma unroll
  for (int i = 0; i < 8; ++i) {
    int4 v = p[i * 1024 + tid];
#pragma unroll
    for (int e = 0; e < E_NUM; ++e)
      c[e] += (v.x == e) + (v.y == e) + (v.z == e) + (v.w == e);
  }
#pragma unroll
  for (int off = 32; off; off >>= 1) {
#pragma unroll
    for (int e = 0; e < E_NUM; ++e) c[e] += __shfl_xor(c[e], off);
  }
  if (lane == 0) {
#pragma unroll
    for (int e = 0; e < E_NUM; ++e) atomicAdd(&hist[e], c[e]);
  }
  __syncthreads();
  if (tid == 0) {
    int acc = 0;
    offs[0] = 0;
#pragma unroll
    for (int e = 0; e < E_NUM; ++e) {
      counts[e] = hist[e];
      cursor[e] = 0;
      acc += ((hist[e] + BMT - 1) / BMT) * BMT;
      offs[e + 1] = acc;
    }
  }
}

// ---------------------------------------------------------------------------
// Scatter: ballot-rank compaction (128 global atomics total). slot_token
// carries the k-flag in bit 31 (k=0 -> fp32 direct-out, k=1 -> outk1).
// ---------------------------------------------------------------------------
__global__ __launch_bounds__(1024) void scatter_kernel(
    const int* __restrict__ eidx, const float* __restrict__ ew,
    const int* __restrict__ offs, int* __restrict__ cursor,
    int* __restrict__ slot_token, float* __restrict__ slot_w) {
  __shared__ int wcnt[16][E_NUM];
  __shared__ int wpre[16][E_NUM];
  __shared__ int bbase[E_NUM];
  __shared__ int soffs[E_NUM];
  const int tid = threadIdx.x, w = tid >> 6, lane = tid & 63;
  const int t = blockIdx.x * 1024 + tid;
  const int2 epair = ((const int2*)eidx)[t];
  const float2 wpair = ((const float2*)ew)[t];
  const int e0 = epair.x, e1 = epair.y;
  const unsigned long long lt = (1ULL << lane) - 1ULL;
  if (tid < E_NUM) soffs[tid] = offs[tid];
  int r0 = 0, r1 = 0;
#pragma unroll
  for (int e = 0; e < E_NUM; ++e) {
    unsigned long long m0 = __ballot(e0 == e);
    unsigned long long m1 = __ballot(e1 == e);
    int c0 = __popcll(m0);
    if (e0 == e) r0 = __popcll(m0 & lt);
    if (e1 == e) r1 = c0 + __popcll(m1 & lt);
    if (lane == 0) wcnt[w][e] = c0 + __popcll(m1);
  }
  __syncthreads();
  if (tid < E_NUM) {
    int run = 0;
#pragma unroll
    for (int w2 = 0; w2 < 16; ++w2) {
      wpre[w2][tid] = run;
      run += wcnt[w2][tid];
    }
    bbase[tid] = atomicAdd(&cursor[tid], run);
  }
  __syncthreads();
  const int s0 = soffs[e0] + bbase[e0] + wpre[w][e0] + r0;
  const int s1 = soffs[e1] + bbase[e1] + wpre[w][e1] + r1;
  slot_token[s0] = t;                       // k=0
  slot_w[s0] = wpair.x;
  slot_token[s1] = t | (int)0x80000000;     // k=1
  slot_w[s1] = wpair.y;
}

// ---------------------------------------------------------------------------
// GEMM core (BK=64) with K-phase stagger: block starts at K-step `phase` and
// wraps (fp32 accumulation is K-order-commutative). phase=0 -> original order.
// ---------------------------------------------------------------------------
template <int KTOT>
__device__ __forceinline__ void gemm_core(const unsigned short* const* aptr,
                                          const unsigned short* const* bptr,
                                          unsigned short* lA, unsigned short* lB,
                                          f32x4 acc[4][4], int phase) {
  const int tid = threadIdx.x;
  const int w = tid >> 6, lane = tid & 63;
  const int wm = w >> 1, wn = w & 1;
  const int rrow = lane & 15;
  const int rq = lane >> 4;
  const int NS = KTOT / BKT;

  for (int s = 0; s < NS; ++s) {
    const int ks = (s + phase) & (NS - 1);
    const int k0 = ks * BKT;
#pragma unroll
    for (int i = 0; i < 4; ++i) {
      load_lds16(aptr[i] + k0, lA + i * 2048 + w * 512);
      load_lds16(bptr[i] + k0, lB + i * 2048 + w * 512);
    }
    __syncthreads();
#pragma unroll
    for (int kk = 0; kk < 2; ++kk) {
      short8 af[4], bfr[4];
#pragma unroll
      for (int mi = 0; mi < 4; ++mi)
        af[mi] = *(const short8*)(lA + (wm * 64 + mi * 16 + rrow) * BKT + kk * 32 + rq * 8);
#pragma unroll
      for (int ni = 0; ni < 4; ++ni)
        bfr[ni] = *(const short8*)(lB + (wn * 64 + ni * 16 + rrow) * BKT + kk * 32 + rq * 8);
#pragma unroll
      for (int mi = 0; mi < 4; ++mi)
#pragma unroll
        for (int ni = 0; ni < 4; ++ni)
          acc[mi][ni] = __builtin_amdgcn_mfma_f32_16x16x32_bf16(af[mi], bfr[ni], acc[mi][ni], 0, 0, 0);
    }
    __syncthreads();
  }
}

// ---------------------------------------------------------------------------
// Unified MoE GEMM dispatch (round-8 diagnosis: fc2's 528 co-started blocks
// run barrier-locked K-loops IN PHASE -> stage/drain fully exposed, 2.4 vs
// 1.03 us per step-slot vs fc1's churn-staggered blocks; memory is proven
// fine: FETCH 85MB, HBM 8.7%). Fix = phase diversity:
//   blocks [0, nf2)      : fc2 for chunk cf2 (+cf2+1 if nf2==528), staggered
//                          K-start, XCD-patch swizzle (round-7, kept: FETCH win)
//   blocks [nf2, nf2+nf1): fc1 for chunk cf1 (unchanged proven structure)
// Mixing fc1 blocks onto every CU gives fc2's drains something to hide under.
// hdn is double-buffered (parity = chunk&1): fc2 reads buf cf2&1 while fc1
// writes buf cf1&1 (cf1 = cf2+1 -> different buffers).
// ---------------------------------------------------------------------------
__global__ __launch_bounds__(256, 2) void moe_gemm(
    const unsigned short* __restrict__ xb, const unsigned short* __restrict__ wc1,
    const float* __restrict__ fc1_b, unsigned short* __restrict__ hdn,
    const unsigned short* __restrict__ wc2, const float* __restrict__ fc2_b,
    const int* __restrict__ offs, const int* __restrict__ counts,
    const int* __restrict__ slot_token, const float* __restrict__ slot_w,
    float* __restrict__ out, unsigned short* __restrict__ outk1,
    int cf2, int cf1, int nf2) {
  __shared__ unsigned short sA[BMT * BKT];
  __shared__ unsigned short sB[BNT * BKT];
  const int id = blockIdx.x;
  const int tid = threadIdx.x;
  const int srow = tid >> 3;            // 8 lanes/row, 16B each over BK=64
  const int scol = (tid & 7) * 8;
  const int w = tid >> 6, lane = tid & 63;
  const int wm = w >> 1, wn = w & 1;
  const int rrow = lane & 15, rq = lane >> 4;

  f32x4 acc[4][4];
  f32x4 zf = {0.f, 0.f, 0.f, 0.f};
#pragma unroll
  for (int mi = 0; mi < 4; ++mi)
#pragma unroll
    for (int ni = 0; ni < 4; ++ni) acc[mi][ni] = zf;

  if (id < nf2) {
    // ---- fc2 path ----
    const int cc  = cf2 + (id >= 264 ? 1 : 0);   // dual-chunk tail support
    const int lid = id - (id >= 264 ? 264 : 0);
    const int xcd = lid & 7, j = lid >> 3;       // j in 0..32
    int ml, nt;
    if (j < 32) { ml = xcd * 4 + (j & 3); nt = j >> 2; }
    else        { ml = 32;                nt = xcd;    }
    const int mt = cc * MT_PER_CHUNK + ml;
    const int row0 = mt * BMT;
    if (row0 >= offs[E_NUM]) return;
    int e = 0;
#pragma unroll
    for (int i = 1; i < E_NUM; ++i) e = (row0 >= offs[i]) ? i : e;
    const int n0 = nt * BNT;

    const unsigned short* A = hdn + (size_t)(cc & 1) * CHUNK_ELEMS +
                              (size_t)(ml * BMT) * DFF_DIM;
    const unsigned short* Bm = wc2 + (size_t)e * H_DIM * DFF_DIM + (size_t)n0 * DFF_DIM;
    const unsigned short* aptr[4];
    const unsigned short* bptr[4];
#pragma unroll
    for (int i = 0; i < 4; ++i) {
      const int r = i * 32 + srow;
      aptr[i] = A + (size_t)r * DFF_DIM + scol;
      bptr[i] = Bm + (size_t)r * DFF_DIM + scol;
    }
    const int phase = (int)((blockIdx.x * 2654435761u) >> 26);  // 0..63
    gemm_core<DFF_DIM>(aptr, bptr, sA, sB, acc, phase);

    const int cnt = counts[e];
    const int lbase = row0 - offs[e];
#pragma unroll
    for (int mi = 0; mi < 4; ++mi) {
#pragma unroll
      for (int j2 = 0; j2 < 4; ++j2) {
        const int rit = wm * 64 + mi * 16 + rq * 4 + j2;
        if (lbase + rit >= cnt) continue;
        const int gr = row0 + rit;
        const int st = slot_token[gr];
        const int tok = st & 0x7FFFFFFF;
        const float wgt = slot_w[gr];
#pragma unroll
        for (int ni = 0; ni < 4; ++ni) {
          const int h = n0 + wn * 64 + ni * 16 + rrow;
          const float v = (acc[mi][ni][j2] + fc2_b[e * H_DIM + h]) * wgt;
          if (st >= 0) out[(size_t)tok * H_DIM + h] = v;            // k=0, fp32
          else         outk1[(size_t)tok * H_DIM + h] = f2bf(v);    // k=1, bf16
        }
      }
    }
  } else {
    // ---- fc1 path ----
    const int fid = id - nf2;
    const int nt = fid & 31, ml = fid >> 5;      // 32 n-tiles x 33 m-tiles
    const int mt = cf1 * MT_PER_CHUNK + ml;
    const int row0 = mt * BMT;
    if (row0 >= offs[E_NUM]) return;
    int e = 0;
#pragma unroll
    for (int i = 1; i < E_NUM; ++i) e = (row0 >= offs[i]) ? i : e;
    const int n0 = nt * BNT;

    const unsigned short* Bm = wc1 + (size_t)e * DFF_DIM * H_DIM + (size_t)n0 * H_DIM;
    const unsigned short* aptr[4];
    const unsigned short* bptr[4];
#pragma unroll
    for (int i = 0; i < 4; ++i) {
      const int r = i * 32 + srow;
      const int tok = slot_token[row0 + r] & 0x7FFFFFFF;
      aptr[i] = xb + (size_t)tok * H_DIM + scol;
      bptr[i] = Bm + (size_t)r * H_DIM + scol;
    }
    gemm_core<H_DIM>(aptr, bptr, sA, sB, acc, 0);

    unsigned short* hw = hdn + (size_t)(cf1 & 1) * CHUNK_ELEMS;
    const int cnt = counts[e];
    const int lbase = row0 - offs[e];
#pragma unroll
    for (int mi = 0; mi < 4; ++mi) {
#pragma unroll
      for (int j2 = 0; j2 < 4; ++j2) {
        const int rit = wm * 64 + mi * 16 + rq * 4 + j2;
        if (lbase + rit >= cnt) continue;
        unsigned short* hrow = hw + (size_t)(ml * BMT + rit) * DFF_DIM;
#pragma unroll
        for (int ni = 0; ni < 4; ++ni) {
          const int n = n0 + wn * 64 + ni * 16 + rrow;
          float v = acc[mi][ni][j2] + fc1_b[e * DFF_DIM + n];
          v = v > 0.f ? v : 0.f;
          hrow[n] = f2bf(v);
        }
      }
    }
  }
}

// ---------------------------------------------------------------------------
// Final add (atomic-free, deterministic): out[t] += bf2f(outk1[t]).
// ---------------------------------------------------------------------------
__global__ __launch_bounds__(256) void add_kernel(
    float* __restrict__ out, const unsigned short* __restrict__ outk1) {
  const int wave = threadIdx.x >> 6;
  const int lane = threadIdx.x & 63;
  const int t = blockIdx.x * 4 + wave;
  float4* orow = (float4*)(out + (size_t)t * H_DIM);
  const ushort4* krow = (const ushort4*)(outk1 + (size_t)t * H_DIM);
#pragma unroll
  for (int j = 0; j < 4; ++j) {
    const int idx = j * 64 + lane;
    float4 a = orow[idx];
    ushort4 b = krow[idx];
    a.x += bf2f(b.x); a.y += bf2f(b.y); a.z += bf2f(b.z); a.w += bf2f(b.w);
    orow[idx] = a;
  }
}

// ---------------------------------------------------------------------------
extern "C" void kernel_launch(void* const* d_in, const int* in_sizes, int n_in,
                              void* d_out, int out_size, void* d_ws, size_t ws_size,
                              hipStream_t stream) {
  const float* x        = (const float*)d_in[0];
  const float* router_w = (const float*)d_in[1];
  const float* router_b = (const float*)d_in[2];
  const float* fc1_w    = (const float*)d_in[3];
  const float* fc1_b    = (const float*)d_in[4];
  const float* fc2_w    = (const float*)d_in[5];
  const float* fc2_b    = (const float*)d_in[6];
  float* out = (float*)d_out;

  char* ws = (char*)d_ws;
  int* counts            = (int*)(ws + WS_COUNTS);
  int* cursor            = (int*)(ws + WS_CURSOR);
  int* offs              = (int*)(ws + WS_OFFS);
  int* slot_token        = (int*)(ws + WS_SLOT_TOK);
  float* slot_w          = (float*)(ws + WS_SLOT_W);
  int* eidx              = (int*)(ws + WS_EIDX);
  float* ew              = (float*)(ws + WS_EW);
  unsigned short* wc1    = (unsigned short*)(ws + WS_WC1);
  unsigned short* wc2    = (unsigned short*)(ws + WS_WC2);
  unsigned short* xb     = (unsigned short*)(ws + WS_XB);
  unsigned short* hdn    = (unsigned short*)(ws + WS_HDN);
  unsigned short* outk1  = (unsigned short*)(ws + WS_OUTK1);

  if (ws_size < WS_REQUIRED) {
    hipMemsetAsync(d_out, 0, (size_t)T_TOKENS * H_DIM * sizeof(float), stream);
    return;  // output stays zero -> diagnosable failure
  }
  hipMemsetAsync(ws, 0, WS_SMALL_ZERO, stream);  // zero counts/cursor/offs/slots

  convert_weights<<<32768, 256, 0, stream>>>(fc1_w, fc2_w, wc1, wc2);
  router_kernel<<<T_TOKENS / 16, 256, 0, stream>>>(x, router_w, router_b, xb, eidx, ew);
  count_kernel<<<1, 1024, 0, stream>>>(eidx, counts, offs, cursor);
  scatter_kernel<<<T_TOKENS / 1024, 1024, 0, stream>>>(eidx, ew, offs, cursor, slot_token, slot_w);

  const int NF1 = 32 * MT_PER_CHUNK;   // 1056 fc1 blocks per chunk
  const int NF2 = 8 * MT_PER_CHUNK;    // 264 fc2 blocks per chunk

  // fc1(0)
  moe_gemm<<<NF1, 256, 0, stream>>>(xb, wc1, fc1_b, hdn, wc2, fc2_b, offs, counts,
                                    slot_token, slot_w, out, outk1, 0, 0, 0);
  // merged: fc2(c) + fc1(c+1), c = 0..5
  for (int c = 0; c < 6; ++c) {
    moe_gemm<<<NF2 + NF1, 256, 0, stream>>>(xb, wc1, fc1_b, hdn, wc2, fc2_b, offs,
                                            counts, slot_token, slot_w, out, outk1,
                                            c, c + 1, NF2);
  }
  // fc1(7)
  moe_gemm<<<NF1, 256, 0, stream>>>(xb, wc1, fc1_b, hdn, wc2, fc2_b, offs, counts,
                                    slot_token, slot_w, out, outk1, 0, 7, 0);
  // dual fc2(6)+fc2(7)
  moe_gemm<<<2 * NF2, 256, 0, stream>>>(xb, wc1, fc1_b, hdn, wc2, fc2_b, offs,
                                        counts, slot_token, slot_w, out, outk1,
                                        6, 0, 2 * NF2);

  add_kernel<<<T_TOKENS / 4, 256, 0, stream>>>(out, outk1);
}

// Round 9
// 1043.348 us; speedup vs baseline: 1.1042x; 1.1042x over previous
//
#include <hip/hip_runtime.h>
#include <stdint.h>

// Problem constants
#define T_TOKENS 16384
#define H_DIM 1024
#define E_NUM 8
#define DFF_DIM 4096

// GEMM tiling
#define BMT 128
#define BNT 128
#define BKT 64
#define MT_CAP 264                       // max padded m-tiles: ceil((32768+8*127)/128)
#define PAD_ROWS (MT_CAP * BMT)          // 33792
#define NCHUNK 4
#define MT_PER_CHUNK (MT_CAP / NCHUNK)   // 66
#define CHUNK_ROWS (MT_PER_CHUNK * BMT)  // 8448
#define M2_PER_CHUNK (CHUNK_ROWS / 64)   // 132 (fc2 64-row m-tiles)

// Workspace layout (bytes) — identical to round 7
#define WS_COUNTS     0
#define WS_CURSOR     32
#define WS_OFFS       64
#define WS_SLOT_TOK   256
#define WS_SLOT_W     135424
#define WS_EIDX       270592
#define WS_EW         401664
#define WS_WC1        532736
#define WS_WC2        67641600
#define WS_XB         134750464
#define WS_HDN        168304896          // CHUNK_ROWS x DFF bf16 = 69,206,016
#define WS_OUTK1      237510912          // T x H bf16 = 33,554,432
#define WS_REQUIRED   271065344UL        // <= 273,162,496 proven available
#define WS_SMALL_ZERO 270592

typedef __attribute__((ext_vector_type(8))) short short8;
typedef __attribute__((ext_vector_type(4))) float f32x4;

__device__ __forceinline__ unsigned short f2bf(float f) {
  union { float f; unsigned int u; } v; v.f = f;
  unsigned int r = v.u + 0x7FFFu + ((v.u >> 16) & 1u);  // round-nearest-even
  return (unsigned short)(r >> 16);
}

__device__ __forceinline__ float bf2f(unsigned short b) {
  union { unsigned int u; float f; } v; v.u = ((unsigned int)b) << 16;
  return v.f;
}

__device__ __forceinline__ void load_lds16(const void* g, void* l) {
  __builtin_amdgcn_global_load_lds(
      (const __attribute__((address_space(1))) void*)g,
      (__attribute__((address_space(3))) void*)l, 16, 0, 0);
}

// ---------------------------------------------------------------------------
// Weight fp32 -> bf16 conversion
// ---------------------------------------------------------------------------
__global__ void convert_weights(const float* __restrict__ w1,
                                const float* __restrict__ w2,
                                unsigned short* __restrict__ wc1,
                                unsigned short* __restrict__ wc2) {
  int i = blockIdx.x * blockDim.x + threadIdx.x;
  const float4* s1 = (const float4*)w1;
  const float4* s2 = (const float4*)w2;
  float4 a = s1[i];
  float4 b = s2[i];
  ushort4 ua, ub;
  ua.x = f2bf(a.x); ua.y = f2bf(a.y); ua.z = f2bf(a.z); ua.w = f2bf(a.w);
  ub.x = f2bf(b.x); ub.y = f2bf(b.y); ub.z = f2bf(b.z); ub.w = f2bf(b.w);
  ((ushort4*)wc1)[i] = ua;
  ((ushort4*)wc2)[i] = ub;
}

// ---------------------------------------------------------------------------
// Router: no global atomics (round-2 lesson). Emits x as bf16 (xb).
// ---------------------------------------------------------------------------
__global__ __launch_bounds__(256) void router_kernel(
    const float* __restrict__ x, const float* __restrict__ rw,
    const float* __restrict__ rb, unsigned short* __restrict__ xb,
    int* __restrict__ eidx, float* __restrict__ ew) {
  __shared__ float4 rws[E_NUM * 256];
  const int tid = threadIdx.x;
#pragma unroll
  for (int k = 0; k < 8; ++k) rws[k * 256 + tid] = ((const float4*)rw)[k * 256 + tid];
  __syncthreads();

  const int wave = tid >> 6;
  const int lane = tid & 63;
#pragma unroll
  for (int i = 0; i < 4; ++i) {
    const int t = blockIdx.x * 16 + wave * 4 + i;
    const float4* xrow = (const float4*)(x + (size_t)t * H_DIM);
    float4 xv[4];
#pragma unroll
    for (int j = 0; j < 4; ++j) xv[j] = xrow[j * 64 + lane];

    ushort4* xbrow = (ushort4*)(xb + (size_t)t * H_DIM);
#pragma unroll
    for (int j = 0; j < 4; ++j) {
      ushort4 o;
      o.x = f2bf(xv[j].x); o.y = f2bf(xv[j].y);
      o.z = f2bf(xv[j].z); o.w = f2bf(xv[j].w);
      xbrow[j * 64 + lane] = o;
    }

    float s[E_NUM];
#pragma unroll
    for (int e = 0; e < E_NUM; ++e) {
      float a = 0.f;
#pragma unroll
      for (int j = 0; j < 4; ++j) {
        float4 wv = rws[e * 256 + j * 64 + lane];
        a += xv[j].x * wv.x + xv[j].y * wv.y + xv[j].z * wv.z + xv[j].w * wv.w;
      }
      s[e] = a;
    }
#pragma unroll
    for (int off = 32; off; off >>= 1) {
#pragma unroll
      for (int e = 0; e < E_NUM; ++e) s[e] += __shfl_xor(s[e], off);
    }
    if (lane == 0) {
      float lg[E_NUM];
#pragma unroll
      for (int e = 0; e < E_NUM; ++e) lg[e] = s[e] + rb[e];
      int i0 = 0; float m0 = lg[0];
#pragma unroll
      for (int e = 1; e < E_NUM; ++e)
        if (lg[e] > m0) { m0 = lg[e]; i0 = e; }
      int i1 = -1; float m1 = -3.4e38f;
#pragma unroll
      for (int e = 0; e < E_NUM; ++e)
        if (e != i0 && lg[e] > m1) { m1 = lg[e]; i1 = e; }
      float e1 = expf(m1 - m0);
      float denom = 1.f + e1;
      ((int2*)eidx)[t] = make_int2(i0, i1);
      ((float2*)ew)[t] = make_float2(1.f / denom, e1 / denom);
    }
  }
}

// ---------------------------------------------------------------------------
// count_kernel: single block, register histogram, LDS atomics only.
// ---------------------------------------------------------------------------
__global__ __launch_bounds__(1024) void count_kernel(const int* __restrict__ eidx,
                                                     int* __restrict__ counts,
                                                     int* __restrict__ offs,
                                                     int* __restrict__ cursor) {
  __shared__ int hist[E_NUM];
  const int tid = threadIdx.x;
  const int lane = tid & 63;
  if (tid < E_NUM) hist[tid] = 0;
  __syncthreads();
  int c[E_NUM];
#pragma unroll
  for (int e = 0; e < E_NUM; ++e) c[e] = 0;
  const int4* p = (const int4*)eidx;
#pragma unroll
  for (int i = 0; i < 8; ++i) {
    int4 v = p[i * 1024 + tid];
#pragma unroll
    for (int e = 0; e < E_NUM; ++e)
      c[e] += (v.x == e) + (v.y == e) + (v.z == e) + (v.w == e);
  }
#pragma unroll
  for (int off = 32; off; off >>= 1) {
#pragma unroll
    for (int e = 0; e < E_NUM; ++e) c[e] += __shfl_xor(c[e], off);
  }
  if (lane == 0) {
#pragma unroll
    for (int e = 0; e < E_NUM; ++e) atomicAdd(&hist[e], c[e]);
  }
  __syncthreads();
  if (tid == 0) {
    int acc = 0;
    offs[0] = 0;
#pragma unroll
    for (int e = 0; e < E_NUM; ++e) {
      counts[e] = hist[e];
      cursor[e] = 0;
      acc += ((hist[e] + BMT - 1) / BMT) * BMT;
      offs[e + 1] = acc;
    }
  }
}

// ---------------------------------------------------------------------------
// Scatter: ballot-rank compaction (128 global atomics total). slot_token
// carries the k-flag in bit 31 (k=0 -> fp32 direct-out, k=1 -> outk1).
// ---------------------------------------------------------------------------
__global__ __launch_bounds__(1024) void scatter_kernel(
    const int* __restrict__ eidx, const float* __restrict__ ew,
    const int* __restrict__ offs, int* __restrict__ cursor,
    int* __restrict__ slot_token, float* __restrict__ slot_w) {
  __shared__ int wcnt[16][E_NUM];
  __shared__ int wpre[16][E_NUM];
  __shared__ int bbase[E_NUM];
  __shared__ int soffs[E_NUM];
  const int tid = threadIdx.x, w = tid >> 6, lane = tid & 63;
  const int t = blockIdx.x * 1024 + tid;
  const int2 epair = ((const int2*)eidx)[t];
  const float2 wpair = ((const float2*)ew)[t];
  const int e0 = epair.x, e1 = epair.y;
  const unsigned long long lt = (1ULL << lane) - 1ULL;
  if (tid < E_NUM) soffs[tid] = offs[tid];
  int r0 = 0, r1 = 0;
#pragma unroll
  for (int e = 0; e < E_NUM; ++e) {
    unsigned long long m0 = __ballot(e0 == e);
    unsigned long long m1 = __ballot(e1 == e);
    int c0 = __popcll(m0);
    if (e0 == e) r0 = __popcll(m0 & lt);
    if (e1 == e) r1 = c0 + __popcll(m1 & lt);
    if (lane == 0) wcnt[w][e] = c0 + __popcll(m1);
  }
  __syncthreads();
  if (tid < E_NUM) {
    int run = 0;
#pragma unroll
    for (int w2 = 0; w2 < 16; ++w2) {
      wpre[w2][tid] = run;
      run += wcnt[w2][tid];
    }
    bbase[tid] = atomicAdd(&cursor[tid], run);
  }
  __syncthreads();
  const int s0 = soffs[e0] + bbase[e0] + wpre[w][e0] + r0;
  const int s1 = soffs[e1] + bbase[e1] + wpre[w][e1] + r1;
  slot_token[s0] = t;                       // k=0
  slot_w[s0] = wpair.x;
  slot_token[s1] = t | (int)0x80000000;     // k=1
  slot_w[s1] = wpair.y;
}

// ---------------------------------------------------------------------------
// GEMM core (BK=64), templated on MI (A rows = MI*32, acc[MI][4]).
// C[(MI*32)x128] = A[(MI*32)xK] * B[128xK]^T. 4 waves; wave owns
// (MI*16)x64 output. No K-phase stagger (round-8 lesson: stagger destroys
// L2 temporal reuse, FETCH x6).
// ---------------------------------------------------------------------------
template <int KTOT, int MI>
__device__ __forceinline__ void gemm_core(const unsigned short* const* aptr,
                                          const unsigned short* const* bptr,
                                          unsigned short* lA, unsigned short* lB,
                                          f32x4 acc[MI][4]) {
  const int tid = threadIdx.x;
  const int w = tid >> 6, lane = tid & 63;
  const int wm = w >> 1, wn = w & 1;
  const int rrow = lane & 15;
  const int rq = lane >> 4;

  for (int ks = 0; ks < KTOT / BKT; ++ks) {
    const int k0 = ks * BKT;
#pragma unroll
    for (int i = 0; i < MI; ++i)
      load_lds16(aptr[i] + k0, lA + i * 2048 + w * 512);
#pragma unroll
    for (int i = 0; i < 4; ++i)
      load_lds16(bptr[i] + k0, lB + i * 2048 + w * 512);
    __syncthreads();
#pragma unroll
    for (int kk = 0; kk < 2; ++kk) {
      short8 af[MI], bfr[4];
#pragma unroll
      for (int mi = 0; mi < MI; ++mi)
        af[mi] = *(const short8*)(lA + (wm * (MI * 16) + mi * 16 + rrow) * BKT + kk * 32 + rq * 8);
#pragma unroll
      for (int ni = 0; ni < 4; ++ni)
        bfr[ni] = *(const short8*)(lB + (wn * 64 + ni * 16 + rrow) * BKT + kk * 32 + rq * 8);
#pragma unroll
      for (int mi = 0; mi < MI; ++mi)
#pragma unroll
        for (int ni = 0; ni < 4; ++ni)
          acc[mi][ni] = __builtin_amdgcn_mfma_f32_16x16x32_bf16(af[mi], bfr[ni], acc[mi][ni], 0, 0, 0);
    }
    __syncthreads();
  }
}

// ---------------------------------------------------------------------------
// fc1: hdn = relu(gather(xb) @ W1^T + b1); 128x128 tile (proven 885 TF).
// ---------------------------------------------------------------------------
__global__ __launch_bounds__(256, 2) void fc1_kernel(
    const unsigned short* __restrict__ xb, const unsigned short* __restrict__ wc1,
    const float* __restrict__ fc1_b, const int* __restrict__ offs,
    const int* __restrict__ counts, const int* __restrict__ slot_token,
    unsigned short* __restrict__ hdn, int chunk) {
  __shared__ unsigned short sA[BMT * BKT];
  __shared__ unsigned short sB[BNT * BKT];
  const int mt = chunk * MT_PER_CHUNK + blockIdx.y;
  const int row0 = mt * BMT;
  if (row0 >= offs[E_NUM]) return;
  int e = 0;
#pragma unroll
  for (int i = 1; i < E_NUM; ++i) e = (row0 >= offs[i]) ? i : e;
  const int n0 = blockIdx.x * BNT;

  f32x4 acc[4][4];
  f32x4 zf = {0.f, 0.f, 0.f, 0.f};
#pragma unroll
  for (int mi = 0; mi < 4; ++mi)
#pragma unroll
    for (int ni = 0; ni < 4; ++ni) acc[mi][ni] = zf;

  const int tid = threadIdx.x;
  const int srow = tid >> 3;            // 8 lanes/row, 16B each over BK=64
  const int scol = (tid & 7) * 8;
  const unsigned short* Bm = wc1 + (size_t)e * DFF_DIM * H_DIM + (size_t)n0 * H_DIM;
  const unsigned short* aptr[4];
  const unsigned short* bptr[4];
#pragma unroll
  for (int i = 0; i < 4; ++i) {
    const int r = i * 32 + srow;
    const int tok = slot_token[row0 + r] & 0x7FFFFFFF;
    aptr[i] = xb + (size_t)tok * H_DIM + scol;
    bptr[i] = Bm + (size_t)r * H_DIM + scol;
  }
  gemm_core<H_DIM, 4>(aptr, bptr, sA, sB, acc);

  const int w = tid >> 6;
  const int lane = tid & 63;
  const int wm = w >> 1, wn = w & 1;
  const int rrow = lane & 15, rq = lane >> 4;
  const int cnt = counts[e];
  const int lbase = row0 - offs[e];
  const int hrow0 = row0 - chunk * CHUNK_ROWS;
#pragma unroll
  for (int mi = 0; mi < 4; ++mi) {
#pragma unroll
    for (int j = 0; j < 4; ++j) {
      const int rit = wm * 64 + mi * 16 + rq * 4 + j;
      if (lbase + rit >= cnt) continue;
      unsigned short* hrow = hdn + (size_t)(hrow0 + rit) * DFF_DIM;
#pragma unroll
      for (int ni = 0; ni < 4; ++ni) {
        const int n = n0 + wn * 64 + ni * 16 + rrow;
        float v = acc[mi][ni][j] + fc1_b[e * DFF_DIM + n];
        v = v > 0.f ? v : 0.f;
        hrow[n] = f2bf(v);
      }
    }
  }
}

// ---------------------------------------------------------------------------
// fc2 v5: 64x128 tile -> 1056 blocks (4.1/CU). Round-9 diagnosis: fc2's 448TF
// sits exactly on the m102 grid-size curve (528 blocks ~ 450TF; 1024 ~ 833);
// per-step drain hiding comes from resident-block churn, which 128x128 tiles
// cap at 2.06/CU (only 8 n-tiles exist). Memory/atomics/occupancy eliminated
// rounds 4-7. XCD slab swizzle (g = xcd*132+j) keeps A-tiles and B-strips
// intra-XCD co-phased (round-8 lesson: NO K-stagger). LDS 24KB, lb(256,4).
// Epilogue: k=0 -> fp32 direct-out, k=1 -> bf16 outk1 (round-7 proven).
// ---------------------------------------------------------------------------
__global__ __launch_bounds__(256, 4) void fc2_kernel(
    const unsigned short* __restrict__ hdn, const unsigned short* __restrict__ wc2,
    const float* __restrict__ fc2_b, const int* __restrict__ offs,
    const int* __restrict__ counts, const int* __restrict__ slot_token,
    const float* __restrict__ slot_w, float* __restrict__ out,
    unsigned short* __restrict__ outk1, int chunk) {
  __shared__ unsigned short sA[64 * BKT];     // 8 KB
  __shared__ unsigned short sB[BNT * BKT];    // 16 KB
  const int id = blockIdx.x;                  // 0..1055
  const int xcd = id & 7, j = id >> 3;        // j in 0..131
  const int g = xcd * M2_PER_CHUNK + j;       // XCD slab: 132 consecutive g
  const int ml = g >> 3;                      // 0..131 (64-row m-tile)
  const int nt = g & 7;
  const int row0 = chunk * CHUNK_ROWS + ml * 64;
  if (row0 >= offs[E_NUM]) return;
  int e = 0;
#pragma unroll
  for (int i = 1; i < E_NUM; ++i) e = (row0 >= offs[i]) ? i : e;
  const int n0 = nt * BNT;

  f32x4 acc[2][4];
  f32x4 zf = {0.f, 0.f, 0.f, 0.f};
#pragma unroll
  for (int mi = 0; mi < 2; ++mi)
#pragma unroll
    for (int ni = 0; ni < 4; ++ni) acc[mi][ni] = zf;

  const int tid = threadIdx.x;
  const int srow = tid >> 3;
  const int scol = (tid & 7) * 8;
  const unsigned short* A = hdn + (size_t)(ml * 64) * DFF_DIM;
  const unsigned short* Bm = wc2 + (size_t)e * H_DIM * DFF_DIM + (size_t)n0 * DFF_DIM;
  const unsigned short* aptr[2];
  const unsigned short* bptr[4];
#pragma unroll
  for (int i = 0; i < 2; ++i)
    aptr[i] = A + (size_t)(i * 32 + srow) * DFF_DIM + scol;
#pragma unroll
  for (int i = 0; i < 4; ++i)
    bptr[i] = Bm + (size_t)(i * 32 + srow) * DFF_DIM + scol;
  gemm_core<DFF_DIM, 2>(aptr, bptr, sA, sB, acc);

  const int w = tid >> 6;
  const int lane = tid & 63;
  const int wm = w >> 1, wn = w & 1;
  const int rrow = lane & 15, rq = lane >> 4;
  const int cnt = counts[e];
  const int lbase = row0 - offs[e];
#pragma unroll
  for (int mi = 0; mi < 2; ++mi) {
#pragma unroll
    for (int j2 = 0; j2 < 4; ++j2) {
      const int rit = wm * 32 + mi * 16 + rq * 4 + j2;
      if (lbase + rit >= cnt) continue;
      const int gr = row0 + rit;
      const int st = slot_token[gr];
      const int tok = st & 0x7FFFFFFF;
      const float wgt = slot_w[gr];
#pragma unroll
      for (int ni = 0; ni < 4; ++ni) {
        const int h = n0 + wn * 64 + ni * 16 + rrow;
        const float v = (acc[mi][ni][j2] + fc2_b[e * H_DIM + h]) * wgt;
        if (st >= 0) out[(size_t)tok * H_DIM + h] = v;            // k=0, fp32
        else         outk1[(size_t)tok * H_DIM + h] = f2bf(v);    // k=1, bf16
      }
    }
  }
}

// ---------------------------------------------------------------------------
// Final add (atomic-free, deterministic): out[t] += bf2f(outk1[t]).
// ---------------------------------------------------------------------------
__global__ __launch_bounds__(256) void add_kernel(
    float* __restrict__ out, const unsigned short* __restrict__ outk1) {
  const int wave = threadIdx.x >> 6;
  const int lane = threadIdx.x & 63;
  const int t = blockIdx.x * 4 + wave;
  float4* orow = (float4*)(out + (size_t)t * H_DIM);
  const ushort4* krow = (const ushort4*)(outk1 + (size_t)t * H_DIM);
#pragma unroll
  for (int j = 0; j < 4; ++j) {
    const int idx = j * 64 + lane;
    float4 a = orow[idx];
    ushort4 b = krow[idx];
    a.x += bf2f(b.x); a.y += bf2f(b.y); a.z += bf2f(b.z); a.w += bf2f(b.w);
    orow[idx] = a;
  }
}

// ---------------------------------------------------------------------------
extern "C" void kernel_launch(void* const* d_in, const int* in_sizes, int n_in,
                              void* d_out, int out_size, void* d_ws, size_t ws_size,
                              hipStream_t stream) {
  const float* x        = (const float*)d_in[0];
  const float* router_w = (const float*)d_in[1];
  const float* router_b = (const float*)d_in[2];
  const float* fc1_w    = (const float*)d_in[3];
  const float* fc1_b    = (const float*)d_in[4];
  const float* fc2_w    = (const float*)d_in[5];
  const float* fc2_b    = (const float*)d_in[6];
  float* out = (float*)d_out;

  char* ws = (char*)d_ws;
  int* counts            = (int*)(ws + WS_COUNTS);
  int* cursor            = (int*)(ws + WS_CURSOR);
  int* offs              = (int*)(ws + WS_OFFS);
  int* slot_token        = (int*)(ws + WS_SLOT_TOK);
  float* slot_w          = (float*)(ws + WS_SLOT_W);
  int* eidx              = (int*)(ws + WS_EIDX);
  float* ew              = (float*)(ws + WS_EW);
  unsigned short* wc1    = (unsigned short*)(ws + WS_WC1);
  unsigned short* wc2    = (unsigned short*)(ws + WS_WC2);
  unsigned short* xb     = (unsigned short*)(ws + WS_XB);
  unsigned short* hdn    = (unsigned short*)(ws + WS_HDN);
  unsigned short* outk1  = (unsigned short*)(ws + WS_OUTK1);

  if (ws_size < WS_REQUIRED) {
    hipMemsetAsync(d_out, 0, (size_t)T_TOKENS * H_DIM * sizeof(float), stream);
    return;  // output stays zero -> diagnosable failure
  }
  hipMemsetAsync(ws, 0, WS_SMALL_ZERO, stream);  // zero counts/cursor/offs/slots

  convert_weights<<<32768, 256, 0, stream>>>(fc1_w, fc2_w, wc1, wc2);
  router_kernel<<<T_TOKENS / 16, 256, 0, stream>>>(x, router_w, router_b, xb, eidx, ew);
  count_kernel<<<1, 1024, 0, stream>>>(eidx, counts, offs, cursor);
  scatter_kernel<<<T_TOKENS / 1024, 1024, 0, stream>>>(eidx, ew, offs, cursor, slot_token, slot_w);

  for (int c = 0; c < NCHUNK; ++c) {
    fc1_kernel<<<dim3(DFF_DIM / BNT, MT_PER_CHUNK), 256, 0, stream>>>(
        xb, wc1, fc1_b, offs, counts, slot_token, hdn, c);
    fc2_kernel<<<8 * M2_PER_CHUNK, 256, 0, stream>>>(
        hdn, wc2, fc2_b, offs, counts, slot_token, slot_w, out, outk1, c);
  }
  add_kernel<<<T_TOKENS / 4, 256, 0, stream>>>(out, outk1);
}